// Round 11
// baseline (267.615 us; speedup 1.0000x reference)
//
#include <hip/hip_runtime.h>
#include <cstdint>

static constexpr int C     = 5;
static constexpr int MAXP  = 10;
static constexpr int MAXV  = 160000;
static constexpr int BLK   = 256;
static constexpr int RBITS = 9;
static constexpr int RBUCK = 1 << RBITS;   // 512 buckets
static constexpr int EPT   = 8;            // elements per thread
static constexpr int ELEMS = BLK * EPT;    // 2048 elements per block

// Output layout (float32, concatenated in reference return order)
static constexpr int VOX_OFF = 0;                           // 160000*10*5
static constexpr int CO_OFF  = MAXV * MAXP * C;             // 8,000,000
static constexpr int NPV_OFF = CO_OFF + MAXV * 3;           // 8,480,000
static constexpr int VN_OFF  = NPV_OFF + MAXV;              // 8,640,000

typedef unsigned long long u64;
static constexpr u64 BYTEMUL = 0x0101010101010101ull;
static constexpr u64 FLAGP   = 1ull << 62;
static constexpr u64 FLAGX   = 2ull << 62;
static constexpr u64 M28     = (1ull << 28) - 1;

// Wave-parallel decoupled lookback, 2 packed fields. Threads 0..63 call;
// result (exclusive prefix) valid on lane 0. Publishes partial then inclusive.
__device__ __forceinline__ void lookback2(u64* status, int b, int tot_h, int tot_v,
                                          int* out_eh, int* out_ev) {
    int lane = threadIdx.x;                   // caller guarantees t < 64
    if (lane == 0) atomicExch(&status[b], FLAGP | ((u64)tot_h << 28) | (u64)tot_v);
    int acc_h = 0, acc_v = 0;
    int w0 = b - 1;
    while (true) {
        int idx = w0 - lane;
        u64 sv = 0;
        if (idx >= 0) {
            long long guard = 0;
            do { sv = atomicAdd(&status[idx], 0ull); guard++; }
            while ((sv >> 62) == 0ull && guard < (1ll << 26));
        }
        u64 mfl = __ballot(idx >= 0 && (sv >> 62) == 2ull);
        int L = mfl ? (__ffsll((unsigned long long)mfl) - 1) : 64;
        int ch = 0, cv = 0;
        if (idx >= 0 && lane <= L) { ch = (int)((sv >> 28) & M28); cv = (int)(sv & M28); }
        for (int o = 32; o > 0; o >>= 1) { ch += __shfl_down(ch, o, 64); cv += __shfl_down(cv, o, 64); }
        acc_h += ch; acc_v += cv;             // lane-0 meaningful
        if (mfl != 0ull) break;               // hit an inclusive: done
        w0 -= 64;
        if (w0 < 0) break;                    // unreachable (block 0 is inclusive)
    }
    if (lane == 0) {
        atomicExch(&status[b], FLAGX | ((u64)(acc_h + tot_h) << 28) | (u64)(acc_v + tot_v));
        *out_eh = acc_h; *out_ev = acc_v;
    }
}

// Wave-parallel lookback, 1 field. Result on lane 0.
__device__ __forceinline__ void lookback1(u64* status, int b, int tot, int* out_e) {
    int lane = threadIdx.x;
    if (lane == 0) atomicExch(&status[b], FLAGP | (u64)tot);
    int acc = 0;
    int w0 = b - 1;
    while (true) {
        int idx = w0 - lane;
        u64 sv = 0;
        if (idx >= 0) {
            long long guard = 0;
            do { sv = atomicAdd(&status[idx], 0ull); guard++; }
            while ((sv >> 62) == 0ull && guard < (1ll << 26));
        }
        u64 mfl = __ballot(idx >= 0 && (sv >> 62) == 2ull);
        int L = mfl ? (__ffsll((unsigned long long)mfl) - 1) : 64;
        int cv = 0;
        if (idx >= 0 && lane <= L) cv = (int)(sv & M28);
        for (int o = 32; o > 0; o >>= 1) cv += __shfl_down(cv, o, 64);
        acc += cv;
        if (mfl != 0ull) break;
        w0 -= 64;
        if (w0 < 0) break;
    }
    if (lane == 0) {
        atomicExch(&status[b], FLAGX | (u64)(acc + tot));
        *out_e = acc;
    }
}

// K1: quantize -> int keys AND pass-0 block histogram; zero lookback statuses.
__global__ void kv11_linhist(const float* __restrict__ pts, const float* __restrict__ vsz,
                             const float* __restrict__ crg, int* __restrict__ key0,
                             int* __restrict__ hist, int* __restrict__ ctrl,
                             u64* __restrict__ statusH, u64* __restrict__ statusW,
                             int NP, int NB, int NWB) {
    __shared__ int sh[RBUCK];
    int t = threadIdx.x, b = blockIdx.x;
    int gid = b * BLK + t;
    if (gid < NB) statusH[gid] = 0ull;
    if (gid < NWB) statusW[gid] = 0ull;
    for (int d = t; d < RBUCK; d += BLK) sh[d] = 0;
    float vx = vsz[0], vy = vsz[1], vz = vsz[2];
    float x0 = crg[0], y0 = crg[1], z0 = crg[2];
    int gx = (int)rintf((crg[3] - x0) / vx);
    int gy = (int)rintf((crg[4] - y0) / vy);
    int gz = (int)rintf((crg[5] - z0) / vz);
    int total = gx * gy * gz;
    if (b == 0 && t == 0) ctrl[2] = total;
    __syncthreads();
    int base = b * ELEMS;
    #pragma unroll
    for (int r = 0; r < EPT; r++) {
        int i = base + r * BLK + t;
        if (i < NP) {
            float px = pts[i * C], py = pts[i * C + 1], pz = pts[i * C + 2];
            int cx = (int)floorf((px - x0) / vx);
            int cy = (int)floorf((py - y0) / vy);
            int cz = (int)floorf((pz - z0) / vz);
            bool valid = (cx >= 0) & (cx < gx) & (cy >= 0) & (cy < gy) & (cz >= 0) & (cz < gz);
            int k = valid ? (cx * gy + cy) * gz + cz : total;
            key0[i] = k;
            atomicAdd(&sh[k & (RBUCK - 1)], 1);
        }
    }
    __syncthreads();
    for (int d = t; d < RBUCK; d += BLK) hist[b * RBUCK + d] = sh[d];
}

// Histogram, passes 1..2 (u64 pairs, digit from high 32 bits).
__global__ void kv11_hist_p(const u64* __restrict__ pair, int* __restrict__ hist,
                            int NP, int shift) {
    __shared__ int sh[RBUCK];
    int t = threadIdx.x, b = blockIdx.x;
    for (int d = t; d < RBUCK; d += BLK) sh[d] = 0;
    __syncthreads();
    int base = b * ELEMS;
    #pragma unroll
    for (int r = 0; r < EPT; r++) {
        int i = base + r * BLK + t;
        if (i < NP) atomicAdd(&sh[(int)((pair[i] >> (32 + shift)) & (RBUCK - 1))], 1);
    }
    __syncthreads();
    for (int d = t; d < RBUCK; d += BLK) hist[b * RBUCK + d] = sh[d];
}

// Per-digit exclusive scan across blocks (grid = RBUCK; block d owns digit d).
__global__ void kv11_scanb(int* __restrict__ hist, int* __restrict__ dtot, int NB) {
    __shared__ int s[BLK];
    __shared__ int carry;
    int d = blockIdx.x, t = threadIdx.x;
    if (t == 0) carry = 0;
    __syncthreads();
    for (int base = 0; base < NB; base += BLK) {
        int b = base + t;
        int v = (b < NB) ? hist[b * RBUCK + d] : 0;
        s[t] = v; __syncthreads();
        for (int o = 1; o < BLK; o <<= 1) {
            int x = (t >= o) ? s[t - o] : 0; __syncthreads();
            s[t] += x; __syncthreads();
        }
        int incl = s[t], c = carry;
        if (b < NB) hist[b * RBUCK + d] = c + incl - v;
        __syncthreads();
        if (t == BLK - 1) carry = c + incl;
        __syncthreads();
    }
    if (t == 0) dtot[d] = carry;
}

// Stable scatter (proven r9 structure): in-block dbase scan, round-tagged whist.
#define SCAT11_BODY(GET_KEY, GET_IDX)                                           \
    __shared__ int cnt[RBUCK];                                                  \
    __shared__ int dbS[RBUCK];                                                  \
    __shared__ int whist[4][RBUCK];                                             \
    int t = threadIdx.x, b = blockIdx.x;                                        \
    int w = t >> 6, lane = t & 63;                                              \
    if (t < 64) {                                                               \
        int loc[8]; int run = 0;                                                \
        _Pragma("unroll")                                                       \
        for (int j = 0; j < 8; j++) { loc[j] = run; run += dtot[t * 8 + j]; }   \
        int tot = run;                                                          \
        for (int o = 1; o < 64; o <<= 1) {                                      \
            int x = __shfl_up(tot, o, 64);                                      \
            if (lane >= o) tot += x;                                            \
        }                                                                       \
        int excl = tot - run;                                                   \
        _Pragma("unroll")                                                       \
        for (int j = 0; j < 8; j++) dbS[t * 8 + j] = excl + loc[j];             \
    }                                                                           \
    for (int x = t; x < 4 * RBUCK; x += BLK) ((int*)whist)[x] = -1;             \
    __syncthreads();                                                            \
    for (int d = t; d < RBUCK; d += BLK) cnt[d] = dbS[d] + hist[b * RBUCK + d]; \
    __syncthreads();                                                            \
    int base = b * ELEMS;                                                       \
    int nc0 = 0, nc1 = 0; bool havenc = false;                                  \
    for (int r = 0; r < EPT; r++) {                                             \
        int i = base + r * BLK + t;                                             \
        bool act = i < NP;                                                      \
        int k = 0, idx = 0, d = 0;                                              \
        if (act) { GET_KEY; GET_IDX; d = (k >> shift) & (RBUCK - 1); }          \
        u64 m = __ballot(act);                                                  \
        _Pragma("unroll")                                                       \
        for (int bit = 0; bit < RBITS; bit++) {                                 \
            u64 bb = __ballot(act && ((d >> bit) & 1));                         \
            m &= ((d >> bit) & 1) ? bb : ~bb;                                   \
        }                                                                       \
        int rw = __popcll(m & ((1ull << lane) - 1ull));                         \
        if (havenc) { cnt[t] = nc0; cnt[t + BLK] = nc1; }                       \
        if (act && rw == 0) whist[w][d] = (r << 20) | (int)__popcll(m);         \
        __syncthreads();                                                        \
        if (act) {                                                              \
            int off = cnt[d];                                                   \
            for (int w2 = 0; w2 < w; w2++) {                                    \
                int e = whist[w2][d];                                           \
                off += ((e >> 20) == r) ? (e & 0xFFFFF) : 0;                    \
            }                                                                   \
            dpair[off + rw] = ((u64)(uint32_t)k << 32) | (uint32_t)idx;         \
        }                                                                       \
        {                                                                       \
            int s0 = 0, s1 = 0;                                                 \
            _Pragma("unroll")                                                   \
            for (int w2 = 0; w2 < 4; w2++) {                                    \
                int e0 = whist[w2][t];                                          \
                int e1 = whist[w2][t + BLK];                                    \
                s0 += ((e0 >> 20) == r) ? (e0 & 0xFFFFF) : 0;                   \
                s1 += ((e1 >> 20) == r) ? (e1 & 0xFFFFF) : 0;                   \
            }                                                                   \
            nc0 = cnt[t] + s0; nc1 = cnt[t + BLK] + s1; havenc = true;          \
        }                                                                       \
        __syncthreads();                                                        \
    }

__global__ void kv11_scat0(const int* __restrict__ skey, u64* __restrict__ dpair,
                           const int* __restrict__ hist, const int* __restrict__ dtot,
                           int NP) {
    const int shift = 0;
    SCAT11_BODY(k = skey[i], idx = i)
}

__global__ void kv11_scatp(const u64* __restrict__ spair, u64* __restrict__ dpair,
                           const int* __restrict__ hist, const int* __restrict__ dtot,
                           int NP, int shift) {
    u64 pv;
    SCAT11_BODY(pv = spair[i]; k = (int)(pv >> 32), idx = (int)(pv & 0xFFFFFFFFull))
}

// FUSED grouping kernel (old heads + scanG + heads2): one pair read, packed
// block scan, wave-parallel lookback for the global head/valid prefix, then
// emit gstart/ghead/byte-flags. Last block publishes G/nval/voxel_num.
__global__ void kv11_group(const u64* __restrict__ pair, int* __restrict__ bsumH,
                           u64* __restrict__ statusH, int* __restrict__ gstart,
                           int* __restrict__ ghead, u64* __restrict__ flags8,
                           int* __restrict__ ctrl, float* __restrict__ out_vnum,
                           int NP, int NP8, int NB) {
    __shared__ int s[BLK];
    __shared__ int eS[2];
    int TOTAL = ctrl[2];
    int t = threadIdx.x, b = blockIdx.x;
    int gid = b * BLK + t;
    if (gid < NP8) flags8[gid] = 0ull;          // zero byte-flag array (set below)
    int sbase = b * ELEMS + t * EPT;
    u64 pv[EPT];
    int hcnt = 0, vcnt = 0;
    unsigned hbits = 0;
    if (sbase < NP) {
        int kprev = (sbase == 0) ? -1 : (int)(pair[sbase - 1] >> 32);
        #pragma unroll
        for (int r = 0; r < EPT; r++) {
            int i = sbase + r;
            if (i < NP) {
                pv[r] = pair[i];
                int k = (int)(pv[r] >> 32);
                int h = (k != TOTAL) && (k != kprev);
                hbits |= (unsigned)h << r;
                hcnt += h;
                vcnt += (k != TOTAL);
                kprev = k;
            }
        }
    }
    s[t] = (hcnt << 16) | vcnt;                 // packed scan; fields <= 2048
    __syncthreads();
    for (int o = 1; o < BLK; o <<= 1) {
        int x = (t >= o) ? s[t - o] : 0; __syncthreads();
        s[t] += x; __syncthreads();
    }
    int incl = s[t];
    int total = s[BLK - 1];
    int tot_h = (total >> 16) & 0xFFFF, tot_v = total & 0xFFFF;
    if (b == 0) {
        if (t == 0) {
            atomicExch(&statusH[0], FLAGX | ((u64)tot_h << 28) | (u64)tot_v);
            eS[0] = 0; eS[1] = 0;
            bsumH[0] = 0;
        }
    } else if (t < 64) {
        int eh, ev;
        lookback2(statusH, b, tot_h, tot_v, &eh, &ev);
        if (t == 0) { eS[0] = eh; eS[1] = ev; bsumH[b] = eh; }
    }
    __syncthreads();
    int excl_h = eS[0];
    if (b == NB - 1 && t == 0) {
        int G = excl_h + tot_h, nval = eS[1] + tot_v;
        ctrl[0] = G; ctrl[1] = nval;
        out_vnum[0] = (float)(G < MAXV ? G : MAXV);
    }
    if (sbase < NP && hbits) {
        int g = excl_h + ((incl >> 16) & 0xFFFF) - hcnt;
        unsigned char* flags = (unsigned char*)flags8;
        #pragma unroll
        for (int r = 0; r < EPT; r++) {
            if ((hbits >> r) & 1) {
                gstart[g] = sbase + r;
                int io = (int)(pv[r] & 0xFFFFFFFFull);
                ghead[g] = io;
                flags[io] = 1;
                g++;
            }
        }
    }
}

// FUSED wpfx kernel: block bytesum scan + wave-parallel lookback.
__global__ void kv11_wp(const u64* __restrict__ flags8, int* __restrict__ wpfx,
                        u64* __restrict__ statusW, int NP8) {
    __shared__ int s[BLK];
    __shared__ int eS;
    int t = threadIdx.x, b = blockIdx.x;
    int i = b * BLK + t;
    u64 wv = (i < NP8) ? flags8[i] : 0ull;
    int v = (int)((wv * BYTEMUL) >> 56);
    s[t] = v;
    __syncthreads();
    for (int o = 1; o < BLK; o <<= 1) {
        int x = (t >= o) ? s[t - o] : 0; __syncthreads();
        s[t] += x; __syncthreads();
    }
    int tot = s[BLK - 1];
    if (b == 0) {
        if (t == 0) { atomicExch(&statusW[0], FLAGX | (u64)tot); eS = 0; }
    } else if (t < 64) {
        int e;
        lookback1(statusW, b, tot, &e);
        if (t == 0) eS = e;
    }
    __syncthreads();
    if (i < NP8) wpfx[i] = eS + s[t] - v;
}

// Tail zero: rows [G, MAXV) of voxels/coors/npv (emit covers rows < G fully).
__global__ void kv11_tail(const int* __restrict__ ctrl, float* __restrict__ out) {
    int G = ctrl[0]; if (G > MAXV) G = MAXV;
    int row = G + blockIdx.x * BLK + threadIdx.x;
    if (row >= MAXV) return;
    float* vrow = out + VOX_OFF + row * MAXP * C;
    #pragma unroll
    for (int j = 0; j < MAXP * C; j++) vrow[j] = 0.f;
    out[CO_OFF + row * 3 + 0] = 0.f;
    out[CO_OFF + row * 3 + 1] = 0.f;
    out[CO_OFF + row * 3 + 2] = 0.f;
    out[NPV_OFF + row] = 0.f;
}

__device__ __forceinline__ int vox_rank(const u64* flags8, const int* wpfx, int io) {
    int w = io >> 3, b8 = io & 7;
    u64 below = flags8[w] & ((1ull << (8 * b8)) - 1ull);
    return wpfx[w] + (int)((below * BYTEMUL) >> 56);
}

// Fused emit: per-element group id via block scan + bsumH; heads write coors/npv
// AND zero-fill the group's unused slots (replaces the 34.5 MB zero kernel).
__global__ void kv11_emit(const u64* __restrict__ pair, const int* __restrict__ gstart,
                          const int* __restrict__ ghead, const u64* __restrict__ flags8,
                          const int* __restrict__ wpfx, const int* __restrict__ ctrl,
                          const int* __restrict__ bsumH, const float* __restrict__ pts,
                          const float* __restrict__ vsz, const float* __restrict__ crg,
                          float* __restrict__ out, int NP) {
    __shared__ int s[BLK];
    int TOTAL = ctrl[2], G = ctrl[0], nval = ctrl[1];
    int t = threadIdx.x, b = blockIdx.x;
    int sbase = b * ELEMS + t * EPT;
    u64 pv[EPT];
    int hcnt = 0;
    unsigned hbits = 0;
    if (sbase < NP) {
        int kprev = (sbase == 0) ? -1 : (int)(pair[sbase - 1] >> 32);
        #pragma unroll
        for (int r = 0; r < EPT; r++) {
            int i = sbase + r;
            if (i < NP) {
                pv[r] = pair[i];
                int k = (int)(pv[r] >> 32);
                int h = (k != TOTAL) && (k != kprev);
                hbits |= (unsigned)h << r;
                hcnt += h;
                kprev = k;
            }
        }
    }
    s[t] = hcnt;
    __syncthreads();
    for (int o = 1; o < BLK; o <<= 1) {
        int x = (t >= o) ? s[t - o] : 0; __syncthreads();
        s[t] += x; __syncthreads();
    }
    if (sbase >= NP) return;
    int gg = bsumH[b] + (s[t] - hcnt) - 1;   // group of element BEFORE this chunk
    int gyd = (int)rintf((crg[4] - crg[1]) / vsz[1]);
    int gzd = (int)rintf((crg[5] - crg[2]) / vsz[2]);
    #pragma unroll
    for (int r = 0; r < EPT; r++) {
        int i = sbase + r;
        if (i >= NP) break;
        int h = (hbits >> r) & 1;
        gg += h;
        u64 p = pv[r];
        int k = (int)(p >> 32);
        if (k == TOTAL) continue;            // sorted suffix of invalids
        int p0 = gstart[gg];
        int vid = vox_rank(flags8, wpfx, ghead[gg]);
        if (vid >= MAXV) continue;
        if (h) {                             // per-voxel work (once per group)
            int cz = k % gzd; int rr = k / gzd; int cy = rr % gyd; int cx = rr / gyd;
            out[CO_OFF + vid * 3 + 0] = (float)cz;
            out[CO_OFF + vid * 3 + 1] = (float)cy;
            out[CO_OFF + vid * 3 + 2] = (float)cx;
            int nxt = (gg + 1 < G) ? gstart[gg + 1] : nval;
            int gsz = nxt - p0;
            int clamped = gsz < MAXP ? gsz : MAXP;
            out[NPV_OFF + vid] = (float)clamped;
            for (int z = clamped; z < MAXP; z++) {   // zero unused slots
                float* dz = out + (vid * MAXP + z) * C;
                dz[0] = 0.f; dz[1] = 0.f; dz[2] = 0.f; dz[3] = 0.f; dz[4] = 0.f;
            }
        }
        int slot = i - p0;
        if (slot >= MAXP) continue;
        int iorig = (int)(p & 0xFFFFFFFFull);
        const float* src = pts + iorig * C;
        float* dst = out + (vid * MAXP + slot) * C;
        dst[0] = src[0]; dst[1] = src[1]; dst[2] = src[2]; dst[3] = src[3]; dst[4] = src[4];
    }
}

extern "C" void kernel_launch(void* const* d_in, const int* in_sizes, int n_in,
                              void* d_out, int out_size, void* d_ws, size_t ws_size,
                              hipStream_t stream) {
    if (!d_out || !d_ws || n_in < 3) return;
    const float* pts = (const float*)d_in[0];
    const float* vsz = (const float*)d_in[1];
    const float* crg = (const float*)d_in[2];
    if (!pts || !vsz || !crg) return;
    const int NP  = in_sizes[0] / C;
    if (NP <= 0) return;
    const int NB  = (NP + ELEMS - 1) / ELEMS;     // 2048-elem blocks (586)
    const int NP8 = (NP + 7) / 8;                 // byte-flag u64 words (150000)
    const int NWB = (NP8 + BLK - 1) / BLK;        // wp blocks (586)

    size_t need = 2ull * NP * 8ull                          // pairA + pairB
                + (size_t)RBUCK * NB * 4ull                 // hist / flags8
                + (size_t)NB * 4ull                         // bsumH
                + (size_t)RBUCK * 4ull                      // dtot
                + (size_t)NP8 * 4ull                        // wpfx
                + 8ull * 4ull + 16ull                       // ctrl, pad
                + (size_t)NB * 8ull + (size_t)NWB * 8ull;   // statusH, statusW
    if (ws_size < need) return;
    if ((size_t)out_size < (size_t)VN_OFF + 1) return;

    u64* pairA = (u64*)d_ws;
    u64* pairB = pairA + NP;
    int* key0  = (int*)pairB;                     // aliases pairB (dead before pass 1 writes)
    int* w     = (int*)(pairB + NP);
    int* hist  = w; w += (size_t)RBUCK * NB;
    u64* flags8 = (u64*)hist;                     // aliases hist (dead after last scatter)
    int* bsumH = w; w += NB;
    int* dtot  = w; w += RBUCK;
    int* wpfx  = w; w += NP8;
    int* ctrl  = w; w += 8;
    w += ((uintptr_t)w & 7) ? 1 : 0;              // 8-byte align
    u64* statusH = (u64*)w;                       // NB words
    u64* statusW = statusH + NB;                  // NWB words

    float* out = (float*)d_out;

    kv11_linhist<<<NB, BLK, 0, stream>>>(pts, vsz, crg, key0, hist, ctrl,
                                         statusH, statusW, NP, NB, NWB);

    // Pass 0: key0 (int) -> pairA
    kv11_scanb<<<RBUCK, BLK, 0, stream>>>(hist, dtot, NB);
    kv11_scat0<<<NB, BLK, 0, stream>>>(key0, pairA, hist, dtot, NP);
    // Pass 1: pairA -> pairB (clobbers key0 — dead)
    kv11_hist_p<<<NB, BLK, 0, stream>>>(pairA, hist, NP, RBITS);
    kv11_scanb<<<RBUCK, BLK, 0, stream>>>(hist, dtot, NB);
    kv11_scatp<<<NB, BLK, 0, stream>>>(pairA, pairB, hist, dtot, NP, RBITS);
    // Pass 2: pairB -> pairA (final sorted order)
    kv11_hist_p<<<NB, BLK, 0, stream>>>(pairB, hist, NP, 2 * RBITS);
    kv11_scanb<<<RBUCK, BLK, 0, stream>>>(hist, dtot, NB);
    kv11_scatp<<<NB, BLK, 0, stream>>>(pairB, pairA, hist, dtot, NP, 2 * RBITS);

    int* gstart = (int*)pairB;                    // pairB free after pass 2
    int* ghead  = gstart + NP;

    kv11_group<<<NB, BLK, 0, stream>>>(pairA, bsumH, statusH, gstart, ghead,
                                       flags8, ctrl, out + VN_OFF, NP, NP8, NB);
    kv11_wp<<<NWB, BLK, 0, stream>>>(flags8, wpfx, statusW, NP8);
    kv11_tail<<<(MAXV + BLK - 1) / BLK, BLK, 0, stream>>>(ctrl, out);
    kv11_emit<<<NB, BLK, 0, stream>>>(pairA, gstart, ghead, flags8, wpfx, ctrl,
                                      bsumH, pts, vsz, crg, out, NP);
}

// Round 12
// 242.527 us; speedup vs baseline: 1.1034x; 1.1034x over previous
//
#include <hip/hip_runtime.h>
#include <cstdint>

static constexpr int C     = 5;
static constexpr int MAXP  = 10;
static constexpr int MAXV  = 160000;
static constexpr int BLK   = 256;
static constexpr int RBITS = 9;
static constexpr int RBUCK = 1 << RBITS;   // 512 buckets
static constexpr int EPT   = 8;            // elements per thread
static constexpr int ELEMS = BLK * EPT;    // 2048 elements per block

// Output layout (float32, concatenated in reference return order)
static constexpr int VOX_OFF = 0;                           // 160000*10*5
static constexpr int CO_OFF  = MAXV * MAXP * C;             // 8,000,000
static constexpr int NPV_OFF = CO_OFF + MAXV * 3;           // 8,480,000
static constexpr int VN_OFF  = NPV_OFF + MAXV;              // 8,640,000

typedef unsigned long long u64;
static constexpr u64 BYTEMUL = 0x0101010101010101ull;

// K1: quantize -> int keys AND pass-0 block histogram (fused).
__global__ void kv12_linhist(const float* __restrict__ pts, const float* __restrict__ vsz,
                             const float* __restrict__ crg, int* __restrict__ key0,
                             int* __restrict__ hist, int* __restrict__ ctrl, int NP) {
    __shared__ int sh[RBUCK];
    int t = threadIdx.x, b = blockIdx.x;
    for (int d = t; d < RBUCK; d += BLK) sh[d] = 0;
    float vx = vsz[0], vy = vsz[1], vz = vsz[2];
    float x0 = crg[0], y0 = crg[1], z0 = crg[2];
    int gx = (int)rintf((crg[3] - x0) / vx);
    int gy = (int)rintf((crg[4] - y0) / vy);
    int gz = (int)rintf((crg[5] - z0) / vz);
    int total = gx * gy * gz;
    if (b == 0 && t == 0) ctrl[2] = total;
    __syncthreads();
    int base = b * ELEMS;
    #pragma unroll
    for (int r = 0; r < EPT; r++) {
        int i = base + r * BLK + t;
        if (i < NP) {
            float px = pts[i * C], py = pts[i * C + 1], pz = pts[i * C + 2];
            int cx = (int)floorf((px - x0) / vx);
            int cy = (int)floorf((py - y0) / vy);
            int cz = (int)floorf((pz - z0) / vz);
            bool valid = (cx >= 0) & (cx < gx) & (cy >= 0) & (cy < gy) & (cz >= 0) & (cz < gz);
            int k = valid ? (cx * gy + cy) * gz + cz : total;
            key0[i] = k;
            atomicAdd(&sh[k & (RBUCK - 1)], 1);
        }
    }
    __syncthreads();
    for (int d = t; d < RBUCK; d += BLK) hist[b * RBUCK + d] = sh[d];
}

// Histogram, passes 1..2 (u64 pairs, digit from high 32 bits).
__global__ void kv12_hist_p(const u64* __restrict__ pair, int* __restrict__ hist,
                            int NP, int shift) {
    __shared__ int sh[RBUCK];
    int t = threadIdx.x, b = blockIdx.x;
    for (int d = t; d < RBUCK; d += BLK) sh[d] = 0;
    __syncthreads();
    int base = b * ELEMS;
    #pragma unroll
    for (int r = 0; r < EPT; r++) {
        int i = base + r * BLK + t;
        if (i < NP) atomicAdd(&sh[(int)((pair[i] >> (32 + shift)) & (RBUCK - 1))], 1);
    }
    __syncthreads();
    for (int d = t; d < RBUCK; d += BLK) hist[b * RBUCK + d] = sh[d];
}

// Per-digit exclusive scan across blocks (grid = RBUCK; block d owns digit d).
__global__ void kv12_scanb(int* __restrict__ hist, int* __restrict__ dtot, int NB) {
    __shared__ int s[BLK];
    __shared__ int carry;
    int d = blockIdx.x, t = threadIdx.x;
    if (t == 0) carry = 0;
    __syncthreads();
    for (int base = 0; base < NB; base += BLK) {
        int b = base + t;
        int v = (b < NB) ? hist[b * RBUCK + d] : 0;
        s[t] = v; __syncthreads();
        for (int o = 1; o < BLK; o <<= 1) {
            int x = (t >= o) ? s[t - o] : 0; __syncthreads();
            s[t] += x; __syncthreads();
        }
        int incl = s[t], c = carry;
        if (b < NB) hist[b * RBUCK + d] = c + incl - v;
        __syncthreads();
        if (t == BLK - 1) carry = c + incl;
        __syncthreads();
    }
    if (t == 0) dtot[d] = carry;
}

// Stable scatter (proven r9 structure): in-block dbase scan, round-tagged whist.
#define SCAT12_BODY(GET_KEY, GET_IDX)                                           \
    __shared__ int cnt[RBUCK];                                                  \
    __shared__ int dbS[RBUCK];                                                  \
    __shared__ int whist[4][RBUCK];                                             \
    int t = threadIdx.x, b = blockIdx.x;                                        \
    int w = t >> 6, lane = t & 63;                                              \
    if (t < 64) {                                                               \
        int loc[8]; int run = 0;                                                \
        _Pragma("unroll")                                                       \
        for (int j = 0; j < 8; j++) { loc[j] = run; run += dtot[t * 8 + j]; }   \
        int tot = run;                                                          \
        for (int o = 1; o < 64; o <<= 1) {                                      \
            int x = __shfl_up(tot, o, 64);                                      \
            if (lane >= o) tot += x;                                            \
        }                                                                       \
        int excl = tot - run;                                                   \
        _Pragma("unroll")                                                       \
        for (int j = 0; j < 8; j++) dbS[t * 8 + j] = excl + loc[j];             \
    }                                                                           \
    for (int x = t; x < 4 * RBUCK; x += BLK) ((int*)whist)[x] = -1;             \
    __syncthreads();                                                            \
    for (int d = t; d < RBUCK; d += BLK) cnt[d] = dbS[d] + hist[b * RBUCK + d]; \
    __syncthreads();                                                            \
    int base = b * ELEMS;                                                       \
    int nc0 = 0, nc1 = 0; bool havenc = false;                                  \
    for (int r = 0; r < EPT; r++) {                                             \
        int i = base + r * BLK + t;                                             \
        bool act = i < NP;                                                      \
        int k = 0, idx = 0, d = 0;                                              \
        if (act) { GET_KEY; GET_IDX; d = (k >> shift) & (RBUCK - 1); }          \
        u64 m = __ballot(act);                                                  \
        _Pragma("unroll")                                                       \
        for (int bit = 0; bit < RBITS; bit++) {                                 \
            u64 bb = __ballot(act && ((d >> bit) & 1));                         \
            m &= ((d >> bit) & 1) ? bb : ~bb;                                   \
        }                                                                       \
        int rw = __popcll(m & ((1ull << lane) - 1ull));                         \
        if (havenc) { cnt[t] = nc0; cnt[t + BLK] = nc1; }                       \
        if (act && rw == 0) whist[w][d] = (r << 20) | (int)__popcll(m);         \
        __syncthreads();                                                        \
        if (act) {                                                              \
            int off = cnt[d];                                                   \
            for (int w2 = 0; w2 < w; w2++) {                                    \
                int e = whist[w2][d];                                           \
                off += ((e >> 20) == r) ? (e & 0xFFFFF) : 0;                    \
            }                                                                   \
            dpair[off + rw] = ((u64)(uint32_t)k << 32) | (uint32_t)idx;         \
        }                                                                       \
        {                                                                       \
            int s0 = 0, s1 = 0;                                                 \
            _Pragma("unroll")                                                   \
            for (int w2 = 0; w2 < 4; w2++) {                                    \
                int e0 = whist[w2][t];                                          \
                int e1 = whist[w2][t + BLK];                                    \
                s0 += ((e0 >> 20) == r) ? (e0 & 0xFFFFF) : 0;                   \
                s1 += ((e1 >> 20) == r) ? (e1 & 0xFFFFF) : 0;                   \
            }                                                                   \
            nc0 = cnt[t] + s0; nc1 = cnt[t + BLK] + s1; havenc = true;          \
        }                                                                       \
        __syncthreads();                                                        \
    }

__global__ void kv12_scat0(const int* __restrict__ skey, u64* __restrict__ dpair,
                           const int* __restrict__ hist, const int* __restrict__ dtot,
                           int NP) {
    const int shift = 0;
    SCAT12_BODY(k = skey[i], idx = i)
}

__global__ void kv12_scatp(const u64* __restrict__ spair, u64* __restrict__ dpair,
                           const int* __restrict__ hist, const int* __restrict__ dtot,
                           int NP, int shift) {
    u64 pv;
    SCAT12_BODY(pv = spair[i]; k = (int)(pv >> 32), idx = (int)(pv & 0xFFFFFFFFull))
}

// Heads + valid flags -> packed per-block sums braw[b]=(h<<16)|v (plain store,
// consumed next kernel). Also zero-fills byte-flag array (set in heads2 — NO
// same-kernel zero/set race, r11's bug).
__global__ void kv12_heads(const u64* __restrict__ pair, int* __restrict__ braw,
                           const int* __restrict__ ctrl, u64* __restrict__ flags8,
                           int NP, int NP8) {
    __shared__ int sh[BLK], sv[BLK];
    int TOTAL = ctrl[2];
    int t = threadIdx.x, b = blockIdx.x;
    int gid = b * BLK + t;
    if (gid < NP8) flags8[gid] = 0ull;
    int sbase = b * ELEMS + t * EPT;
    int hs = 0, vs = 0;
    if (sbase < NP) {
        int kprev = (sbase == 0) ? -1 : (int)(pair[sbase - 1] >> 32);
        #pragma unroll
        for (int r = 0; r < EPT; r++) {
            int i = sbase + r;
            if (i < NP) {
                int k = (int)(pair[i] >> 32);
                if (k != TOTAL) { vs++; hs += (k != kprev); }
                kprev = k;
            }
        }
    }
    sh[t] = hs; sv[t] = vs;
    __syncthreads();
    for (int o = BLK / 2; o > 0; o >>= 1) {
        if (t < o) { sh[t] += sh[t + o]; sv[t] += sv[t + o]; }
        __syncthreads();
    }
    if (t == 0) braw[b] = (sh[0] << 16) | sv[0];
}

// Heads2: wave-0 no-spin walk over published braw partials -> exclusive prefix
// (replaces the serialized single-block scanG); writes bsumH[b]; last block
// publishes G/nval/voxel_num. Then emits gstart/ghead/byte flags as in r9.
__global__ void kv12_heads2(const u64* __restrict__ pair, const int* __restrict__ braw,
                            int* __restrict__ bsumH, int* __restrict__ gstart,
                            int* __restrict__ ghead, u64* __restrict__ flags8,
                            int* __restrict__ ctrl, float* __restrict__ out_vnum,
                            int NP, int NB) {
    __shared__ int s[BLK];
    __shared__ int eS;
    int TOTAL = ctrl[2];
    int t = threadIdx.x, b = blockIdx.x;
    if (t < 64) {                           // exclusive prefix of braw[0..b)
        int eh = 0, ev = 0;
        for (int base = 0; base < b; base += 64) {
            int idx = base + t;
            int pb = (idx < b) ? braw[idx] : 0;
            int hh = (pb >> 16) & 0xFFFF, vv = pb & 0xFFFF;
            #pragma unroll
            for (int o = 32; o > 0; o >>= 1) {
                hh += __shfl_down(hh, o, 64);
                vv += __shfl_down(vv, o, 64);
            }
            eh += hh; ev += vv;             // meaningful on lane 0
        }
        if (t == 0) {
            eS = eh;
            bsumH[b] = eh;
            if (b == NB - 1) {
                int own = braw[b];
                int G = eh + ((own >> 16) & 0xFFFF);
                int nval = ev + (own & 0xFFFF);
                ctrl[0] = G; ctrl[1] = nval;
                out_vnum[0] = (float)(G < MAXV ? G : MAXV);
            }
        }
    }
    int sbase = b * ELEMS + t * EPT;
    u64 pv[EPT];
    int hcnt = 0;
    unsigned hbits = 0;
    if (sbase < NP) {
        int kprev = (sbase == 0) ? -1 : (int)(pair[sbase - 1] >> 32);
        #pragma unroll
        for (int r = 0; r < EPT; r++) {
            int i = sbase + r;
            if (i < NP) {
                pv[r] = pair[i];
                int k = (int)(pv[r] >> 32);
                int h = (k != TOTAL) && (k != kprev);
                hbits |= (unsigned)h << r;
                hcnt += h;
                kprev = k;
            }
        }
    }
    s[t] = hcnt;
    __syncthreads();                        // also publishes eS
    for (int o = 1; o < BLK; o <<= 1) {
        int x = (t >= o) ? s[t - o] : 0; __syncthreads();
        s[t] += x; __syncthreads();
    }
    if (sbase < NP && hbits) {
        int g = eS + s[t] - hcnt;
        unsigned char* flags = (unsigned char*)flags8;
        #pragma unroll
        for (int r = 0; r < EPT; r++) {
            if ((hbits >> r) & 1) {
                gstart[g] = sbase + r;
                int io = (int)(pv[r] & 0xFFFFFFFFull);
                ghead[g] = io;
                flags[io] = 1;
                g++;
            }
        }
    }
}

// wpA: per-block bytesum of byte-flag words (plain store, consumed next kernel).
__global__ void kv12_wpA(const u64* __restrict__ flags8, int* __restrict__ wsum, int NP8) {
    __shared__ int s[BLK];
    int t = threadIdx.x, i = blockIdx.x * BLK + t;
    u64 wv = (i < NP8) ? flags8[i] : 0ull;
    s[t] = (int)((wv * BYTEMUL) >> 56);
    __syncthreads();
    for (int o = BLK / 2; o > 0; o >>= 1) { if (t < o) s[t] += s[t + o]; __syncthreads(); }
    if (t == 0) wsum[blockIdx.x] = s[0];
}

// wp2: wave-0 no-spin walk over wsum partials + in-block scan -> wpfx
// (replaces serialized wpB + wpC).
__global__ void kv12_wp2(const u64* __restrict__ flags8, const int* __restrict__ wsum,
                         int* __restrict__ wpfx, int NP8) {
    __shared__ int s[BLK];
    __shared__ int eS;
    int t = threadIdx.x, b = blockIdx.x;
    if (t < 64) {
        int acc = 0;
        for (int base = 0; base < b; base += 64) {
            int idx = base + t;
            int v = (idx < b) ? wsum[idx] : 0;
            #pragma unroll
            for (int o = 32; o > 0; o >>= 1) v += __shfl_down(v, o, 64);
            acc += v;
        }
        if (t == 0) eS = acc;
    }
    int i = b * BLK + t;
    u64 wv = (i < NP8) ? flags8[i] : 0ull;
    int v = (int)((wv * BYTEMUL) >> 56);
    s[t] = v;
    __syncthreads();                        // also publishes eS
    for (int o = 1; o < BLK; o <<= 1) {
        int x = (t >= o) ? s[t - o] : 0; __syncthreads();
        s[t] += x; __syncthreads();
    }
    if (i < NP8) wpfx[i] = eS + s[t] - v;
}

// Zero-fill voxels + coors + npv (contiguous float4 — near-HBM-peak; r11 showed
// scattering this into emit costs ~2x in RMW line amplification).
__global__ void kv12_zero(float4* __restrict__ out4, int n4) {
    int i = blockIdx.x * BLK + threadIdx.x;
    if (i < n4) out4[i] = make_float4(0.f, 0.f, 0.f, 0.f);
}

__device__ __forceinline__ int vox_rank(const u64* flags8, const int* wpfx, int io) {
    int w = io >> 3, b8 = io & 7;
    u64 below = flags8[w] & ((1ull << (8 * b8)) - 1ull);
    return wpfx[w] + (int)((below * BYTEMUL) >> 56);
}

// Fused emit: per-element group id via block scan + bsumH; heads write coors/npv.
__global__ void kv12_emit(const u64* __restrict__ pair, const int* __restrict__ gstart,
                          const int* __restrict__ ghead, const u64* __restrict__ flags8,
                          const int* __restrict__ wpfx, const int* __restrict__ ctrl,
                          const int* __restrict__ bsumH, const float* __restrict__ pts,
                          const float* __restrict__ vsz, const float* __restrict__ crg,
                          float* __restrict__ out, int NP) {
    __shared__ int s[BLK];
    int TOTAL = ctrl[2], G = ctrl[0], nval = ctrl[1];
    int t = threadIdx.x, b = blockIdx.x;
    int sbase = b * ELEMS + t * EPT;
    u64 pv[EPT];
    int hcnt = 0;
    unsigned hbits = 0;
    if (sbase < NP) {
        int kprev = (sbase == 0) ? -1 : (int)(pair[sbase - 1] >> 32);
        #pragma unroll
        for (int r = 0; r < EPT; r++) {
            int i = sbase + r;
            if (i < NP) {
                pv[r] = pair[i];
                int k = (int)(pv[r] >> 32);
                int h = (k != TOTAL) && (k != kprev);
                hbits |= (unsigned)h << r;
                hcnt += h;
                kprev = k;
            }
        }
    }
    s[t] = hcnt;
    __syncthreads();
    for (int o = 1; o < BLK; o <<= 1) {
        int x = (t >= o) ? s[t - o] : 0; __syncthreads();
        s[t] += x; __syncthreads();
    }
    if (sbase >= NP) return;
    int gg = bsumH[b] + (s[t] - hcnt) - 1;   // group of element BEFORE this chunk
    int gyd = (int)rintf((crg[4] - crg[1]) / vsz[1]);
    int gzd = (int)rintf((crg[5] - crg[2]) / vsz[2]);
    #pragma unroll
    for (int r = 0; r < EPT; r++) {
        int i = sbase + r;
        if (i >= NP) break;
        int h = (hbits >> r) & 1;
        gg += h;
        u64 p = pv[r];
        int k = (int)(p >> 32);
        if (k == TOTAL) continue;            // sorted suffix of invalids
        int p0 = gstart[gg];
        int vid = vox_rank(flags8, wpfx, ghead[gg]);
        if (vid >= MAXV) continue;
        if (h) {                             // per-voxel work (once per group)
            int cz = k % gzd; int rr = k / gzd; int cy = rr % gyd; int cx = rr / gyd;
            out[CO_OFF + vid * 3 + 0] = (float)cz;
            out[CO_OFF + vid * 3 + 1] = (float)cy;
            out[CO_OFF + vid * 3 + 2] = (float)cx;
            int nxt = (gg + 1 < G) ? gstart[gg + 1] : nval;
            int gsz = nxt - p0;
            out[NPV_OFF + vid] = (float)(gsz < MAXP ? gsz : MAXP);
        }
        int slot = i - p0;
        if (slot >= MAXP) continue;
        int iorig = (int)(p & 0xFFFFFFFFull);
        const float* src = pts + iorig * C;
        float* dst = out + (vid * MAXP + slot) * C;
        dst[0] = src[0]; dst[1] = src[1]; dst[2] = src[2]; dst[3] = src[3]; dst[4] = src[4];
    }
}

extern "C" void kernel_launch(void* const* d_in, const int* in_sizes, int n_in,
                              void* d_out, int out_size, void* d_ws, size_t ws_size,
                              hipStream_t stream) {
    if (!d_out || !d_ws || n_in < 3) return;
    const float* pts = (const float*)d_in[0];
    const float* vsz = (const float*)d_in[1];
    const float* crg = (const float*)d_in[2];
    if (!pts || !vsz || !crg) return;
    const int NP  = in_sizes[0] / C;
    if (NP <= 0) return;
    const int NB  = (NP + ELEMS - 1) / ELEMS;     // 2048-elem blocks (586)
    const int NP8 = (NP + 7) / 8;                 // byte-flag u64 words (150000)
    const int NWB = (NP8 + BLK - 1) / BLK;        // wp blocks (586)

    size_t need = 2ull * NP * 8ull                          // pairA + pairB
                + (size_t)RBUCK * NB * 4ull                 // hist / flags8
                + 2ull * NB * 4ull                          // braw, bsumH
                + (size_t)RBUCK * 4ull                      // dtot
                + (size_t)NP8 * 4ull                        // wpfx
                + (size_t)NWB * 4ull + 8ull * 4ull;         // wsum, ctrl
    if (ws_size < need) return;
    if ((size_t)out_size < (size_t)VN_OFF + 1) return;

    u64* pairA = (u64*)d_ws;
    u64* pairB = pairA + NP;
    int* key0  = (int*)pairB;                     // aliases pairB (dead before pass 1 writes)
    int* w     = (int*)(pairB + NP);
    int* hist  = w; w += (size_t)RBUCK * NB;
    u64* flags8 = (u64*)hist;                     // aliases hist (dead after last scatter)
    int* braw  = w; w += NB;
    int* bsumH = w; w += NB;
    int* dtot  = w; w += RBUCK;
    int* wpfx  = w; w += NP8;
    int* wsum  = w; w += NWB;
    int* ctrl  = w; w += 8;

    float* out = (float*)d_out;

    kv12_linhist<<<NB, BLK, 0, stream>>>(pts, vsz, crg, key0, hist, ctrl, NP);
    kv12_zero<<<(VN_OFF / 4 + BLK - 1) / BLK, BLK, 0, stream>>>((float4*)out, VN_OFF / 4);

    // Pass 0: key0 (int) -> pairA
    kv12_scanb<<<RBUCK, BLK, 0, stream>>>(hist, dtot, NB);
    kv12_scat0<<<NB, BLK, 0, stream>>>(key0, pairA, hist, dtot, NP);
    // Pass 1: pairA -> pairB (clobbers key0 — dead)
    kv12_hist_p<<<NB, BLK, 0, stream>>>(pairA, hist, NP, RBITS);
    kv12_scanb<<<RBUCK, BLK, 0, stream>>>(hist, dtot, NB);
    kv12_scatp<<<NB, BLK, 0, stream>>>(pairA, pairB, hist, dtot, NP, RBITS);
    // Pass 2: pairB -> pairA (final sorted order)
    kv12_hist_p<<<NB, BLK, 0, stream>>>(pairB, hist, NP, 2 * RBITS);
    kv12_scanb<<<RBUCK, BLK, 0, stream>>>(hist, dtot, NB);
    kv12_scatp<<<NB, BLK, 0, stream>>>(pairB, pairA, hist, dtot, NP, 2 * RBITS);

    int* gstart = (int*)pairB;                    // pairB free after pass 2
    int* ghead  = gstart + NP;

    kv12_heads<<<NB, BLK, 0, stream>>>(pairA, braw, ctrl, flags8, NP, NP8);
    kv12_heads2<<<NB, BLK, 0, stream>>>(pairA, braw, bsumH, gstart, ghead, flags8,
                                        ctrl, out + VN_OFF, NP, NB);
    kv12_wpA<<<NWB, BLK, 0, stream>>>(flags8, wsum, NP8);
    kv12_wp2<<<NWB, BLK, 0, stream>>>(flags8, wsum, wpfx, NP8);
    kv12_emit<<<NB, BLK, 0, stream>>>(pairA, gstart, ghead, flags8, wpfx, ctrl,
                                      bsumH, pts, vsz, crg, out, NP);
}